// Round 4
// 3062.595 us; speedup vs baseline: 1.1340x; 1.1340x over previous
//
#include <hip/hip_runtime.h>
#include <hip/hip_bf16.h>

#define T_STEPS 256
#define BATCH 64
#define HID 512
#define GATES 3072
#define NLAYERS 4
#define BT_GROUPS 4
#define GBLK 32            // blocks per bt-group (each owns 16 h-cols)
#define SCAN_THREADS 256
#define HSTR 520           // h-tile LDS k-stride (elems); 1040 B, 16B-aligned rows
#define GLP 84             // gl float stride (80 + pad)
#define POLL_VALVE 4096    // bounded spin: worst case ~1.2 ms/step, fails fast not hangs

typedef __bf16 bf16_t;
typedef _Float16 fp16_t;
typedef __attribute__((ext_vector_type(8))) __bf16 bf16x8;
typedef __attribute__((ext_vector_type(4))) float f32x4;
typedef __attribute__((ext_vector_type(4))) unsigned int u32x4;

__device__ __forceinline__ float sigm(float x){ return 1.0f/(1.0f + __expf(-x)); }
__device__ __forceinline__ float tanh_f(float x){ return 2.0f/(1.0f + __expf(-2.0f*x)) - 1.0f; }
__device__ __forceinline__ unsigned short f2bf(float x){ __bf16 b=(__bf16)x; return __builtin_bit_cast(unsigned short, b); }

// ---- transpose fp32 [R][C] -> bf16 [C][R] ----
__global__ void transpose_cast_kernel(const float* __restrict__ src, unsigned short* __restrict__ dst, int R, int C){
  __shared__ float tile[32][33];
  int tx = threadIdx.x & 31, ty = threadIdx.x >> 5;
  int c0 = blockIdx.x*32, r0 = blockIdx.y*32;
  #pragma unroll
  for(int i=0;i<4;i++){ int r = r0 + ty + i*8; tile[ty+i*8][tx] = src[(size_t)r*C + c0 + tx]; }
  __syncthreads();
  #pragma unroll
  for(int i=0;i<4;i++){ int c = c0 + ty + i*8; dst[(size_t)c*R + r0 + tx] = f2bf(tile[tx][ty+i*8]); }
}

// ---- inputs (B,T,D) fp32 -> masked bf16 (T,B,D) ----
__global__ void prep_x0_kernel(const float* __restrict__ inp, const int* __restrict__ lens, unsigned short* __restrict__ x0){
  int idx = blockIdx.x*blockDim.x + threadIdx.x;
  int e = idx*4;
  int d = e & (HID-1);
  int tb = e >> 9;
  int b = tb & (BATCH-1);
  int t = tb >> 6;
  const float4 v = *(const float4*)(inp + ((size_t)b*T_STEPS + t)*HID + d);
  float m = (t < lens[b]) ? 1.f : 0.f;
  ushort4 u; u.x=f2bf(v.x*m); u.y=f2bf(v.y*m); u.z=f2bf(v.z*m); u.w=f2bf(v.w*m);
  *(ushort4*)(x0 + ((size_t)t*BATCH + b)*HID + d) = u;
}

// ---- xi GEMM: C[m][n] = A[m][:] @ BT[n][:],  M=16384, N=3072, K=512, out fp16 ----
__global__ void __launch_bounds__(256,2)
xi_gemm_kernel(const unsigned short* __restrict__ A,   // [16384][512] bf16
               const unsigned short* __restrict__ BT,  // [3072][512] bf16 (WihT)
               fp16_t* __restrict__ C)                  // [16384][3072] fp16
{
  __shared__ __align__(16) unsigned short As[128*72];
  __shared__ __align__(16) unsigned short Bs[128*72];
  const int tid = threadIdx.x, lane = tid & 63, wv = tid >> 6;
  const int frow = lane & 15, quad = lane >> 4;
  const int m0 = blockIdx.x*128, n0 = blockIdx.y*128;
  const int mh = (wv>>1)*64, nh = (wv&1)*64;
  const int sr = tid>>1, sk = (tid&1)*32;
  f32x4 acc[4][4];
  #pragma unroll
  for(int mt=0;mt<4;mt++)
    #pragma unroll
    for(int nt=0;nt<4;nt++) acc[mt][nt] = (f32x4){0.f,0.f,0.f,0.f};

  for(int kc=0;kc<512;kc+=64){
    #pragma unroll
    for(int i=0;i<4;i++){
      *(uint4*)(As + sr*72 + sk + i*8) = *(const uint4*)(A + (size_t)(m0+sr)*512 + kc + sk + i*8);
      *(uint4*)(Bs + sr*72 + sk + i*8) = *(const uint4*)(BT + (size_t)(n0+sr)*512 + kc + sk + i*8);
    }
    __syncthreads();
    #pragma unroll
    for(int ks=0;ks<2;ks++){
      bf16x8 av[4], bv[4];
      #pragma unroll
      for(int mt=0;mt<4;mt++) av[mt] = *(const bf16x8*)(As + (mh+mt*16+frow)*72 + ks*32 + quad*8);
      #pragma unroll
      for(int nt=0;nt<4;nt++) bv[nt] = *(const bf16x8*)(Bs + (nh+nt*16+frow)*72 + ks*32 + quad*8);
      #pragma unroll
      for(int mt=0;mt<4;mt++)
        #pragma unroll
        for(int nt=0;nt<4;nt++)
          acc[mt][nt] = __builtin_amdgcn_mfma_f32_16x16x32_bf16(av[mt], bv[nt], acc[mt][nt],0,0,0);
    }
    __syncthreads();
  }
  #pragma unroll
  for(int mt=0;mt<4;mt++)
    #pragma unroll
    for(int nt=0;nt<4;nt++)
      #pragma unroll
      for(int r4=0;r4<4;r4++)
        C[(size_t)(m0+mh+mt*16+quad*4+r4)*GATES + n0+nh+nt*16+frow] = (fp16_t)acc[mt][nt][r4];
}

// ---- fused per-layer scan (h-recurrence only; xi precomputed) ----
// Cross-block h exchange is SELF-FLAGGING: per-step slots Hseq[s][64][512] bf16,
// pre-filled with 0xFF (bf16 NaN pattern -- unproducible by finite math; masked
// rows give exact 0.0). A dword == 0xFFFFFFFF means "not yet written"; dword
// stores are atomic, so torn data is impossible. The poll loads ARE the data loads.
//
// RULE-18 FENCE (the round-1/2 bug): sentinel compares are register-only VALU
// ops; hipcc may hoist them past an inline-asm s_waitcnt with only a "memory"
// clobber, reading hv BEFORE the loads land. Fix: the waitcnt asm takes
// hv[0..3] as "+v" operands (hard dataflow dependency) + sched_barrier(0).
//
// BOUNDED SPIN (round-3 lesson): valve at 4096 iterations + s_sleep backoff so
// a broken protocol fails fast with NaN instead of killing the container, and
// poll traffic can't starve producer stores on the fabric.
//
// ZERO-GROWTH ALIASING:
//  - non-rev layers: Hseq[s][b][h] == output[t][b][h] (tcur==s) -> Hseq ALIASES
//    the output buffer; the publish IS the output write.
//  - rev layers: Hseq aliases a DEAD buffer (layer1: xA, consumed by gemm1
//    before the memset; layer3: x0, consumed by gemm2). Outputs go to xdst/dout.
__global__ void __launch_bounds__(SCAN_THREADS,1)
scan_kernel(const fp16_t* __restrict__ Xi,             // [T*B][3072] fp16
            const unsigned short* __restrict__ WhhT,   // [2560][512] bf16
            const float* __restrict__ bias_l,
            const int* __restrict__ lens,
            unsigned short* __restrict__ Hseq,         // [T][64][512] bf16, 0xFF-sentinel
            unsigned short* __restrict__ xdst,         // bf16 (T,B,H); rev layers only
            float* __restrict__ dout,                  // fp32 (B,T,H); last layer only
            int rev)
{
  __shared__ __align__(16) unsigned short Al[16*HSTR];
  __shared__ float gl[64*GLP];
  __shared__ float bl[80];
  __shared__ int ll[16];

  const int tid = threadIdx.x;
  const int bt  = blockIdx.x & (BT_GROUPS-1);
  const int g   = blockIdx.x >> 2;                     // 0..31
  const int lane = tid & 63, wv = tid >> 6;
  const int frow = lane & 15, quad = lane >> 4;

  for(int i=tid;i<80;i+=SCAN_THREADS) bl[i] = bias_l[(i>>4)*HID + g*16 + (i&15)];
  if(tid<16) ll[tid] = lens[bt*16+tid];
  __syncthreads();

  // register-resident W_hh fragments: 5 gate tiles x 4 ksteps (kstep = wv + 4j)
  bf16x8 Bf[5][4];
  #pragma unroll
  for(int q=0;q<5;q++)
    #pragma unroll
    for(int j=0;j<4;j++)
      Bf[q][j] = *(const bf16x8*)(WhhT + (size_t)(q*HID + g*16 + frow)*HID + (wv + j*4)*32 + quad*8);

  // combine constants: each thread owns one (row, col)
  const int cr = tid >> 4;           // 0..15
  const int jj = tid & 15;           // 0..15
  const int brow_g = bt*16 + cr;
  const int hcol   = g*16 + jj;
  const int L_r = ll[cr];
  float cst=0.f, hs=0.f;
  unsigned short hbf=0; int tprev=0;

  // poll addresses are loop-invariant except for the slot offset
  const size_t pofs[4] = {
    (size_t)((tid      )>>6)*HID + (size_t)((tid      )&63)*8,
    (size_t)((tid+256  )>>6)*HID + (size_t)((tid+256  )&63)*8,
    (size_t)((tid+512  )>>6)*HID + (size_t)((tid+512  )&63)*8,
    (size_t)((tid+768  )>>6)*HID + (size_t)((tid+768  )&63)*8 };

  for(int s=0; s<T_STEPS; s++){
    // ---- phase 1 (rev only): outputs for previous step (fire-and-forget) ----
    if(rev && s>0){
      if(dout) dout[((size_t)brow_g*T_STEPS + tprev)*HID + hcol] = hs;
      else     xdst[((size_t)tprev*BATCH + brow_g)*HID + hcol] = hbf;
    }

    // ---- phase 2: xi prefetch (overlaps poll latency) + poll h(s-1) ----
    bool valid = s < L_r;
    int tcur = rev ? (valid ? (L_r-1-s) : s) : s;
    const fp16_t* xr = Xi + ((size_t)tcur*BATCH + brow_g)*GATES + hcol;
    fp16_t x0v=xr[0], x1v=xr[512], x2v=xr[1024], x3v=xr[1536], x4v=xr[2048], x5v=xr[2560];

    u32x4 hv[4];
    if(s==0){
      #pragma unroll
      for(int i=0;i<4;i++) hv[i] = (u32x4){0u,0u,0u,0u};
    } else {
      const unsigned short* hb = Hseq + (size_t)(s-1)*BATCH*HID + (size_t)bt*16*HID;
      int it = 0;
      while(1){
        #pragma unroll
        for(int i=0;i<4;i++){
          const unsigned short* p = hb + pofs[i];
          asm volatile("global_load_dwordx4 %0, %1, off sc0 sc1" : "=v"(hv[i]) : "v"(p) : "memory");
        }
        // RULE-18 FENCE: tie hv to the waitcnt via "+v" so the sentinel
        // compares below CANNOT be scheduled before the loads complete.
        asm volatile("s_waitcnt vmcnt(0)"
                     : "+v"(hv[0]), "+v"(hv[1]), "+v"(hv[2]), "+v"(hv[3])
                     :: "memory");
        __builtin_amdgcn_sched_barrier(0);
        unsigned int bad = 0u;
        #pragma unroll
        for(int i=0;i<4;i++){
          bad |= (unsigned)(hv[i][0] == 0xFFFFFFFFu);
          bad |= (unsigned)(hv[i][1] == 0xFFFFFFFFu);
          bad |= (unsigned)(hv[i][2] == 0xFFFFFFFFu);
          bad |= (unsigned)(hv[i][3] == 0xFFFFFFFFu);
        }
        if(!bad) break;
        if(++it > POLL_VALVE) break;        // fail fast (NaN), never hang
        __builtin_amdgcn_s_sleep(1);        // ~64 cy backoff: don't hammer the fabric
      }
    }
    #pragma unroll
    for(int i=0;i<4;i++){
      int idx = tid + i*256;
      *(u32x4*)(Al + (idx>>6)*HSTR + (idx&63)*8) = hv[i];
    }
    __syncthreads();  // b2: h staged

    // ---- phase 3: MFMAs (K split mod 4 across waves) + gate partials to LDS ----
    f32x4 acc[5];
    #pragma unroll
    for(int q=0;q<5;q++) acc[q] = (f32x4){0.f,0.f,0.f,0.f};
    #pragma unroll
    for(int j=0;j<4;j++){
      bf16x8 a = *(const bf16x8*)((const bf16_t*)Al + (size_t)frow*HSTR + (wv + j*4)*32 + quad*8);
      #pragma unroll
      for(int q=0;q<5;q++)
        acc[q] = __builtin_amdgcn_mfma_f32_16x16x32_bf16(a, Bf[q][j], acc[q],0,0,0);
    }
    #pragma unroll
    for(int q=0;q<5;q++)
      #pragma unroll
      for(int r4=0;r4<4;r4++)
        gl[(wv*16 + quad*4 + r4)*GLP + q*16 + frow] = acc[q][r4];   // C: col=lane&15, row=quad*4+reg
    __syncthreads();  // b3

    // ---- phase 4: combine + direct publish of h(s) from registers ----
    {
      float ga[5];
      #pragma unroll
      for(int q=0;q<5;q++){
        float sum = bl[q*16+jj];
        #pragma unroll
        for(int w=0;w<4;w++) sum += gl[(w*16+cr)*GLP + q*16 + jj];
        ga[q] = sum;
      }
      ga[0] += (float)x0v; ga[1] += (float)x1v; ga[2] += (float)x2v;
      ga[3] += (float)x3v; ga[4] += (float)x4v;
      float m = valid ? 1.f : 0.f;
      float gi=sigm(ga[0]), gf=sigm(ga[1]), gcv=tanh_f(ga[2]), go=sigm(ga[3]), grv=sigm(ga[4]);
      cst = (gf*cst + gi*gcv) * m;
      hs  = (grv*(go*tanh_f(cst)) + (1.f-grv)*(float)x5v) * m;
      hbf = f2bf(hs);
      tprev = tcur;

      // pair-pack neighboring cols so every store is a whole (atomic) dword
      int up = __shfl_down((int)(unsigned int)hbf, 1);
      if((jj&1)==0){
        unsigned int packed = (unsigned int)hbf | (((unsigned int)up & 0xFFFFu) << 16);
        unsigned int* dst = (unsigned int*)(Hseq + (size_t)s*BATCH*HID + (size_t)brow_g*HID + hcol);
        asm volatile("global_store_dword %0, %1, off sc0 sc1" :: "v"(dst), "v"(packed) : "memory");
      }
    }
    // no barrier needed here: next-iter Al writes are fenced from this iter's
    // phase-3 Al reads by b3; next-iter gl writes are fenced from this iter's
    // phase-4 gl reads by next-iter b2.
  }

  // epilogue (rev only): outputs for step T-1
  if(rev){
    if(dout) dout[((size_t)brow_g*T_STEPS + tprev)*HID + hcol] = hs;
    else     xdst[((size_t)tprev*BATCH + brow_g)*HID + hcol] = hbf;
  }
}

extern "C" void kernel_launch(void* const* d_in, const int* in_sizes, int n_in,
                              void* d_out, int out_size, void* d_ws, size_t ws_size,
                              hipStream_t stream){
  const float* inp    = (const float*)d_in[0];
  const float* weight = (const float*)d_in[1];
  const float* bias   = (const float*)d_in[2];
  const int*   lens   = (const int*)d_in[3];
  float* dout = (float*)d_out;

  char* ws = (char*)d_ws;
  size_t off = 0;
  const size_t WTL = (size_t)(3072+2560)*512;   // per-layer transposed bf16 elements
  unsigned short* WT = (unsigned short*)(ws+off); off += (size_t)NLAYERS*WTL*2;        // 23.1 MB
  unsigned short* x0 = (unsigned short*)(ws+off); off += (size_t)T_STEPS*BATCH*HID*2;  // 16.8 MB
  unsigned short* xA = (unsigned short*)(ws+off); off += (size_t)T_STEPS*BATCH*HID*2;  // 16.8 MB
  fp16_t* Xi = (fp16_t*)(ws+off); off += (size_t)T_STEPS*BATCH*GATES*2;                // 100.7 MB
  // total 157.3 MB -- no growth vs the proven layout (Hseq aliases x0/xA)

  const size_t HSEQ_BYTES = (size_t)T_STEPS*BATCH*HID*2;                               // 16.8 MB

  const size_t WS_L = (size_t)512*3072 + (size_t)512*2560; // per-layer fp32 weight elements
  for(int l=0;l<NLAYERS;l++){
    const float* wih = weight + l*WS_L;
    const float* whh = wih + (size_t)512*3072;
    unsigned short* wihT = WT + l*WTL;
    unsigned short* whhT = wihT + (size_t)3072*512;
    transpose_cast_kernel<<<dim3(3072/32,512/32),256,0,stream>>>(wih, wihT, 512, 3072);
    transpose_cast_kernel<<<dim3(2560/32,512/32),256,0,stream>>>(whh, whhT, 512, 2560);
  }
  prep_x0_kernel<<<8192,256,0,stream>>>(inp, lens, x0);

  // layer plan (Hseq aliases only dead or output buffers):
  //  l=0: gemm reads x0 -> Hseq = output = xA          (non-rev: publish IS output)
  //  l=1: gemm reads xA -> Hseq = xA (dead), out = x0  (rev)
  //  l=2: gemm reads x0 -> Hseq = output = xA          (non-rev)
  //  l=3: gemm reads xA -> Hseq = x0 (dead), out = dout (rev)
  const unsigned short* gemm_in[4] = {x0, xA, x0, xA};
  unsigned short*       hseq_l[4]  = {xA, xA, xA, x0};
  unsigned short*       xdst_l[4]  = {nullptr, x0, nullptr, nullptr};

  for(int l=0;l<NLAYERS;l++){
    xi_gemm_kernel<<<dim3(128,24),256,0,stream>>>(gemm_in[l], WT + l*WTL, Xi);
    hipMemsetAsync(hseq_l[l], 0xFF, HSEQ_BYTES, stream);  // sentinel fill (after gemm consumed it)
    scan_kernel<<<BT_GROUPS*GBLK, SCAN_THREADS, 0, stream>>>(
        Xi, WT + l*WTL + (size_t)3072*512,
        bias + (size_t)l*2560, lens, hseq_l[l],
        xdst_l[l], (l==3) ? dout : nullptr, l&1);
  }
}